// Round 7
// baseline (2731.093 us; speedup 1.0000x reference)
//
#include <hip/hip_runtime.h>
#include <hip/hip_bf16.h>
#include <hip/hip_cooperative_groups.h>

namespace cg = cooperative_groups;

#define N_NODES 50000
#define N_EDGES 800000
#define NC 16
#define FDIM 13
#define HID 32
#define RT_ROW 528     // 16 outputs * 32 hidden + 16 b2-terms (bf16)
#define EPB 64         // edges per msg tile
#define BSHIFT 3       // nodes per bucket = 8
#define NBUCK 6400     // ceil(50000/8) padded to 256*25
#define ZWORDS 56400   // deg(50000 f32) + hist(6400 i32)
#define MTILE 12500    // 800000/64 edge tiles

typedef unsigned short ushort_t;
typedef unsigned int uint_t;
typedef __attribute__((ext_vector_type(8))) unsigned short u16x8;

__device__ __forceinline__ float bf2f(ushort_t u) {
  union { unsigned int i; float f; } v; v.i = ((unsigned int)u) << 16; return v.f;
}
__device__ __forceinline__ ushort_t f2bf(float f) {
  union { unsigned int i; float f; } v; v.f = f;
  unsigned int r = v.i + 0x7FFFu + ((v.i >> 16) & 1u);   // RNE
  return (ushort_t)(r >> 16);
}
__device__ __forceinline__ float loadf(const void* p, int i, int isf32) {
  return isf32 ? ((const float*)p)[i] : bf2f(((const ushort_t*)p)[i]);
}
__device__ __forceinline__ float sigmoidf_(float x) { return 1.0f / (1.0f + __expf(-x)); }
__device__ __forceinline__ float tanhf_(float x) { return 1.0f - 2.0f / (__expf(2.0f * x) + 1.0f); }

struct MK {
  const void *hx_in, *ef; const int *src, *dst;
  const void *w1, *b1, *w2, *b2, *wih, *whh, *bihp, *bhhp;
  float *hx32, *agg, *deg; int *flag, *hist, *seid;
  ushort_t *hidden, *Rt; void *out;
};

struct ScanSh { int lds[NBUCK]; int psum[256]; };                       // 26,624 B
struct RnSh   { float w2t[256 * 36]; float b2s[256]; };                 // 37,888 B
struct MlpSh  { float w1s[FDIM * HID]; float b1s[HID]; };               //  1,792 B
struct GruSh  { float wihT[816]; float whhT[816]; float bihs[48]; float bhhs[48]; };
struct MsgSh  { float hs[EPB * 33]; int ssrc[EPB]; int sdst[EPB]; int sei[EPB]; };
union  ShMem  { ScanSh scan; RnSh rn; MlpSh mlp; GruSh gru; MsgSh msg; }; // 37,888 B

// ---- phase: zero deg+hist; block 0 detects input dtype (1 = fp32) ----
static __device__ void ph_init(const MK& a, int* cnt, int bid, int nb) {
  int tid = threadIdx.x;
  int* zb = (int*)a.deg;                       // deg+hist contiguous
  for (int i = bid * 256 + tid; i < ZWORDS; i += nb * 256) zb[i] = 0;
  if (bid == 0) {
    if (tid == 0) *cnt = 0;
    __syncthreads();
    uint_t lo = ((const uint_t*)a.hx_in)[tid] & 0xFFFFu;
    uint_t ex = (lo >> 7) & 0xFFu;
    int wild = (ex < 103u || ex > 151u) ? 1 : 0;
    if (lo == 0u || lo == 0x8000u) wild = 0;
    atomicAdd(cnt, wild);
    __syncthreads();
    if (tid == 0) a.flag[0] = (*cnt > 64) ? 1 : 0;
  }
}

// ---- phase: hx->fp32, deg/hist atomics, + MLP hidden (edge order, streaming) ----
static __device__ void ph_pre(MlpSh& sh, const MK& a, int bid, int nb, int isf32, int do_mlp) {
  int tid = threadIdx.x;
  if (do_mlp) {
    for (int k = tid; k < FDIM * HID; k += 256) sh.w1s[k] = loadf(a.w1, k, isf32);
    if (tid < HID) sh.b1s[tid] = loadf(a.b1, tid, isf32);
    __syncthreads();
  }
  for (int base = bid * 256; base < N_EDGES; base += nb * 256) {
    int idx = base + tid;                      // N_EDGES == N_NODES*NC == 800000
    a.hx32[idx] = loadf(a.hx_in, idx, isf32);
    atomicAdd(&a.deg[a.dst[idx]], 1.0f);
    atomicAdd(&a.hist[a.src[idx] >> BSHIFT], 1);
    if (do_mlp) {
      float efr[FDIM];
      #pragma unroll
      for (int i = 0; i < FDIM; i++) efr[i] = loadf(a.ef, idx * FDIM + i, isf32);
      u16x8* hrow = (u16x8*)(a.hidden + (size_t)idx * HID);
      #pragma unroll
      for (int c = 0; c < 4; c++) {
        u16x8 ov;
        #pragma unroll
        for (int j = 0; j < 8; j++) {
          int h = c * 8 + j;
          float acc = sh.b1s[h];
          #pragma unroll
          for (int i = 0; i < FDIM; i++) acc += efr[i] * sh.w1s[i * HID + h];
          ov[j] = f2bf(fmaxf(acc, 0.0f));
        }
        hrow[c] = ov;
      }
    }
  }
}

// ---- phase: exclusive scan of hist (single block) ----
static __device__ void ph_scan(ScanSh& sh, const MK& a) {
  int t = threadIdx.x;
  for (int i = t; i < NBUCK; i += 256) sh.lds[i] = a.hist[i];
  __syncthreads();
  int base = t * 25, s = 0;
  #pragma unroll
  for (int i = 0; i < 25; i++) { int v = sh.lds[base + i]; sh.lds[base + i] = s; s += v; }
  sh.psum[t] = s;
  __syncthreads();
  if (t == 0) { int run = 0; for (int i = 0; i < 256; i++) { int v = sh.psum[i]; sh.psum[i] = run; run += v; } }
  __syncthreads();
  int off = sh.psum[t];
  #pragma unroll
  for (int i = 0; i < 25; i++) sh.lds[base + i] += off;
  __syncthreads();
  for (int i = t; i < NBUCK; i += 256) a.hist[i] = sh.lds[i];
}

// ---- phase: scatter eids into bucket order (hist = running cursors) ----
static __device__ void ph_scatter(const MK& a, int bid, int nb) {
  int tid = threadIdx.x;
  for (int base = bid * 256; base < N_EDGES; base += nb * 256) {
    int e = base + tid;
    int p = atomicAdd(&a.hist[a.src[e] >> BSHIFT], 1);
    a.seid[p] = e;
  }
}

// ---- phase: Rt build from hx32 + agg zero ----
static __device__ void ph_rnode(RnSh& sh, const MK& a, int bid, int nb, int isf32) {
  int tid = threadIdx.x;
  for (int k = tid; k < 256 * HID; k += 256) {
    int h = k >> 8, io = k & 255;
    sh.w2t[io * 36 + h] = loadf(a.w2, h * 256 + io, isf32);
  }
  sh.b2s[tid] = loadf(a.b2, tid, isf32);
  __syncthreads();
  for (int base = bid * 256; base < N_EDGES; base += nb * 256) {
    int idx = base + tid;
    a.agg[idx] = 0.0f;
    int node = idx >> 4, o = idx & 15;
    float hxr[16];
    const float4* hp = (const float4*)(a.hx32 + node * NC);
    #pragma unroll
    for (int q = 0; q < 4; q++) {
      float4 t = hp[q];
      hxr[4 * q + 0] = t.x; hxr[4 * q + 1] = t.y; hxr[4 * q + 2] = t.z; hxr[4 * q + 3] = t.w;
    }
    ushort_t* rowp = a.Rt + (size_t)node * RT_ROW;
    #pragma unroll
    for (int c = 0; c < 4; c++) {
      float acc8[8] = {0, 0, 0, 0, 0, 0, 0, 0};
      #pragma unroll
      for (int i = 0; i < 16; i++) {
        const float* wp = &sh.w2t[(i * 16 + o) * 36 + c * 8];
        float4 wa = *(const float4*)(wp);
        float4 wb = *(const float4*)(wp + 4);
        acc8[0] += hxr[i] * wa.x; acc8[1] += hxr[i] * wa.y; acc8[2] += hxr[i] * wa.z; acc8[3] += hxr[i] * wa.w;
        acc8[4] += hxr[i] * wb.x; acc8[5] += hxr[i] * wb.y; acc8[6] += hxr[i] * wb.z; acc8[7] += hxr[i] * wb.w;
      }
      u16x8 ov;
      #pragma unroll
      for (int j = 0; j < 8; j++) ov[j] = f2bf(acc8[j]);
      *(u16x8*)(rowp + o * 32 + c * 8) = ov;
    }
    float vb = 0.0f;
    #pragma unroll
    for (int i = 0; i < 16; i++) vb += hxr[i] * sh.b2s[i * 16 + o];
    rowp[512 + o] = f2bf(vb);
  }
}

// ---- phase: edge message (sorted eids; gather hidden rows; dot Rt; scatter agg) ----
static __device__ void ph_msg(MsgSh& sh, const MK& a, int bid, int nb) {
  int tid = threadIdx.x;
  for (int t = bid; t < MTILE; t += nb) {
    int e0 = t * EPB;
    if (tid < EPB) {
      int eid = a.seid[e0 + tid];
      sh.sei[tid] = eid;
      sh.ssrc[tid] = a.src[eid];
      sh.sdst[tid] = a.dst[eid];
    }
    __syncthreads();
    // gather hidden: 64 rows * 64 B; 4 threads per row, u16x8 chunks
    {
      int row = tid >> 2, chunk = tid & 3;
      u16x8 hv = ((const u16x8*)(a.hidden + (size_t)sh.sei[row] * HID))[chunk];
      #pragma unroll
      for (int j = 0; j < 8; j++) sh.hs[row * 33 + chunk * 8 + j] = bf2f(hv[j]);
    }
    __syncthreads();
    #pragma unroll
    for (int q = 0; q < 4; q++) {
      int item = q * 256 + tid;
      int le = item >> 4, o = item & 15;
      int s = sh.ssrc[le], d = sh.sdst[le];
      const ushort_t* rrow = a.Rt + (size_t)s * RT_ROW;
      const u16x8* rr = (const u16x8*)(rrow + o * 32);
      float acc = bf2f(rrow[512 + o]);
      #pragma unroll
      for (int c = 0; c < 4; c++) {
        u16x8 rv = rr[c];
        #pragma unroll
        for (int j = 0; j < 8; j++) acc += sh.hs[le * 33 + c * 8 + j] * bf2f(rv[j]);
      }
      atomicAdd(&a.agg[d * NC + o], acc);
    }
    __syncthreads();
  }
}

// GRU weight staging transposed stride-17 (conflict-free) + core
static __device__ void stage_gru(GruSh& g, const MK& a, int isf32) {
  int tid = threadIdx.x;
  for (int kk = tid; kk < 3 * NC * NC; kk += 256) {
    int gg = kk >> 8, rem = kk & 255, o = rem >> 4, k = rem & 15;
    g.wihT[gg * 272 + k * 17 + o] = loadf(a.wih, kk, isf32);
    g.whhT[gg * 272 + k * 17 + o] = loadf(a.whh, kk, isf32);
  }
  if (tid < 3 * NC) { g.bihs[tid] = loadf(a.bihp, tid, isf32); g.bhhs[tid] = loadf(a.bhhp, tid, isf32); }
}
static __device__ float gru_core(const GruSh& g, const float* x, const float* h, int o) {
  float gir = g.bihs[o], giz = g.bihs[NC + o], gin = g.bihs[2 * NC + o];
  float ghr = g.bhhs[o], ghz = g.bhhs[NC + o], ghn = g.bhhs[2 * NC + o];
  #pragma unroll
  for (int k = 0; k < NC; k++) {
    gir += x[k] * g.wihT[k * 17 + o];
    giz += x[k] * g.wihT[272 + k * 17 + o];
    gin += x[k] * g.wihT[544 + k * 17 + o];
    ghr += h[k] * g.whhT[k * 17 + o];
    ghz += h[k] * g.whhT[272 + k * 17 + o];
    ghn += h[k] * g.whhT[544 + k * 17 + o];
  }
  float r = sigmoidf_(gir + ghr);
  float z = sigmoidf_(giz + ghz);
  float n = tanhf_(gin + r * ghn);
  return (1.0f - z) * n + z * h[o];
}

__device__ __forceinline__ void load_xh(const MK& a, int v, float inv, float* x, float* h) {
  const float4* ar = (const float4*)(a.agg + v * NC);
  const float4* hr = (const float4*)(a.hx32 + v * NC);
  #pragma unroll
  for (int q = 0; q < 4; q++) {
    float4 aa = ar[q], bb = hr[q];
    x[4 * q + 0] = aa.x * inv; x[4 * q + 1] = aa.y * inv; x[4 * q + 2] = aa.z * inv; x[4 * q + 3] = aa.w * inv;
    h[4 * q + 0] = bb.x; h[4 * q + 1] = bb.y; h[4 * q + 2] = bb.z; h[4 * q + 3] = bb.w;
  }
}

// ---- phase: GRU update in place (reads before writes within same wave-group) ----
static __device__ void ph_gruup(GruSh& sh, const MK& a, int bid, int nb, int isf32) {
  int tid = threadIdx.x;
  stage_gru(sh, a, isf32);
  __syncthreads();
  for (int base = bid * 256; base < N_EDGES; base += nb * 256) {
    int idx = base + tid;
    int v = idx >> 4, o = idx & 15;
    float inv = 1.0f / fmaxf(a.deg[v], 1.0f);
    float x[16], h[16];
    load_xh(a, v, inv, x, h);
    float hn = gru_core(sh, x, h, o);
    a.hx32[idx] = hn;            // row read by its own 16-lane group only (same wave)
  }
}

// ---- phase: final GRU -> d_out ----
static __device__ void ph_gruout(GruSh& sh, const MK& a, int bid, int nb, int isf32) {
  int tid = threadIdx.x;
  stage_gru(sh, a, isf32);
  __syncthreads();
  for (int base = bid * 256; base < N_EDGES; base += nb * 256) {
    int idx = base + tid;
    int v = idx >> 4, o = idx & 15;
    float inv = 1.0f / fmaxf(a.deg[v], 1.0f);
    float x[16], h[16];
    load_xh(a, v, inv, x, h);
    float hn = gru_core(sh, x, h, o);
    if (isf32) ((float*)a.out)[idx] = hn;
    else       ((ushort_t*)a.out)[idx] = f2bf(hn);
  }
}

// ================= cooperative megakernel =================
__global__ void __launch_bounds__(256, 4) mega(MK a) {
  __shared__ ShMem sh;
  int bid = blockIdx.x, nb = gridDim.x;
  cg::grid_group grid = cg::this_grid();
  ph_init(a, &sh.scan.psum[0], bid, nb);
  grid.sync();
  int isf32 = a.flag[0];
  ph_pre(sh.mlp, a, bid, nb, isf32, 1);
  grid.sync();
  if (bid == 0) ph_scan(sh.scan, a);
  grid.sync();
  ph_scatter(a, bid, nb);
  ph_rnode(sh.rn, a, bid, nb, isf32);
  grid.sync();
  ph_msg(sh.msg, a, bid, nb);
  grid.sync();
  ph_gruup(sh.gru, a, bid, nb, isf32);
  grid.sync();
  ph_rnode(sh.rn, a, bid, nb, isf32);
  grid.sync();
  ph_msg(sh.msg, a, bid, nb);
  grid.sync();
  ph_gruout(sh.gru, a, bid, nb, isf32);
}

// ================= plain-dispatch fallbacks =================
__global__ void w_init(MK a)   { __shared__ int c; ph_init(a, &c, blockIdx.x, gridDim.x); }
__global__ void w_pre(MK a, int m) { __shared__ MlpSh s; ph_pre(s, a, blockIdx.x, gridDim.x, a.flag[0], m); }
__global__ void w_scan(MK a)   { __shared__ ScanSh s; ph_scan(s, a); }
__global__ void w_scat(MK a)   { ph_scatter(a, blockIdx.x, gridDim.x); }
__global__ void w_rnode(MK a)  { __shared__ RnSh s; ph_rnode(s, a, blockIdx.x, gridDim.x, a.flag[0]); }
__global__ void w_msg(MK a)    { __shared__ MsgSh s; ph_msg(s, a, blockIdx.x, gridDim.x); }
__global__ void w_gruup(MK a)  { __shared__ GruSh s; ph_gruup(s, a, blockIdx.x, gridDim.x, a.flag[0]); }
__global__ void w_gruout(MK a) { __shared__ GruSh s; ph_gruout(s, a, blockIdx.x, gridDim.x, a.flag[0]); }

// small-ws fallback: unsorted edges, MLP recomputed per tile (R5/R6-proven)
__global__ void __launch_bounds__(256) k_msg_rec(MK a) {
  __shared__ float w1s[FDIM * HID], b1s[HID];
  __shared__ float efs[EPB * FDIM], hs[EPB * 33];
  __shared__ int ssrc[EPB], sdst[EPB];
  int isf32 = a.flag[0];
  int tid = threadIdx.x, e0 = blockIdx.x * EPB;
  for (int k = tid; k < FDIM * HID; k += 256) w1s[k] = loadf(a.w1, k, isf32);
  if (tid < HID) b1s[tid] = loadf(a.b1, tid, isf32);
  if (tid < EPB) { ssrc[tid] = a.src[e0 + tid]; sdst[tid] = a.dst[e0 + tid]; }
  __syncthreads();
  #pragma unroll
  for (int q = 0; q < 4; q++) {
    int j = q * 256 + tid, le = j >> 4, i = j & 15;
    if (i < FDIM) efs[le * FDIM + i] = loadf(a.ef, (e0 + le) * FDIM + i, isf32);
  }
  __syncthreads();
  for (int v = tid; v < EPB * HID; v += 256) {
    int le = v >> 5, h = v & 31;
    float acc = b1s[h];
    #pragma unroll
    for (int i = 0; i < FDIM; i++) acc += efs[le * FDIM + i] * w1s[i * HID + h];
    hs[le * 33 + h] = fmaxf(acc, 0.0f);
  }
  __syncthreads();
  #pragma unroll
  for (int q = 0; q < 4; q++) {
    int item = q * 256 + tid, le = item >> 4, o = item & 15;
    int s = ssrc[le], d = sdst[le];
    const ushort_t* rrow = a.Rt + (size_t)s * RT_ROW;
    const u16x8* rr = (const u16x8*)(rrow + o * 32);
    float acc = bf2f(rrow[512 + o]);
    #pragma unroll
    for (int c = 0; c < 4; c++) {
      u16x8 rv = rr[c];
      #pragma unroll
      for (int j = 0; j < 8; j++) acc += hs[le * 33 + c * 8 + j] * bf2f(rv[j]);
    }
    atomicAdd(&a.agg[d * NC + o], acc);
  }
}

extern "C" void kernel_launch(void* const* d_in, const int* in_sizes, int n_in,
                              void* d_out, int out_size, void* d_ws, size_t ws_size,
                              hipStream_t stream) {
  char* ws = (char*)d_ws;
  MK a;
  a.hx_in = d_in[0]; a.ef = d_in[1];
  a.src = (const int*)d_in[2]; a.dst = (const int*)d_in[3];
  a.w1 = d_in[4]; a.b1 = d_in[5]; a.w2 = d_in[6]; a.b2 = d_in[7];
  a.wih = d_in[8]; a.whh = d_in[9]; a.bihp = d_in[10]; a.bhhp = d_in[11];
  a.hx32 = (float*)(ws + 0);                   //  3,200,000
  a.agg  = (float*)(ws + 3200000);             //  3,200,000
  a.flag = (int*)  (ws + 6400000);             //        256
  a.deg  = (float*)(ws + 6400256);             //    200,000 (deg+hist = zero region)
  a.hist = (int*)  (ws + 6600256);             //     25,600
  a.out  = d_out;

  int big = (ws_size >= (size_t)113825856);
  if (big) {
    a.seid   = (int*)(ws + 6625856);           //  3,200,000
    a.hidden = (ushort_t*)(ws + 9825856);      // 51,200,000
    a.Rt     = (ushort_t*)(ws + 61025856);     // 52,800,000 -> ends 113,825,856
    void* kargs[] = { (void*)&a };
    hipError_t le = hipLaunchCooperativeKernel((const void*)mega, dim3(1024), dim3(256),
                                               kargs, 0, stream);
    if (le == hipSuccess) return;
    (void)hipGetLastError();                   // clear; use plain-dispatch path
    w_init<<<(ZWORDS + 255) / 256, 256, 0, stream>>>(a);
    w_pre<<<3125, 256, 0, stream>>>(a, 1);
    w_scan<<<1, 256, 0, stream>>>(a);
    w_scat<<<3125, 256, 0, stream>>>(a);
    w_rnode<<<3125, 256, 0, stream>>>(a);
    w_msg<<<MTILE, 256, 0, stream>>>(a);
    w_gruup<<<3125, 256, 0, stream>>>(a);
    w_rnode<<<3125, 256, 0, stream>>>(a);
    w_msg<<<MTILE, 256, 0, stream>>>(a);
    w_gruout<<<3125, 256, 0, stream>>>(a);
  } else {
    a.seid = (int*)(ws + 6625856);             // unused
    a.hidden = (ushort_t*)(ws + 6625856);      // unused
    a.Rt = (ushort_t*)(ws + 6625856);          // 52,800,000 -> ends 59,425,856
    w_init<<<(ZWORDS + 255) / 256, 256, 0, stream>>>(a);
    w_pre<<<3125, 256, 0, stream>>>(a, 0);
    w_rnode<<<3125, 256, 0, stream>>>(a);
    k_msg_rec<<<MTILE, 256, 0, stream>>>(a);
    w_gruup<<<3125, 256, 0, stream>>>(a);
    w_rnode<<<3125, 256, 0, stream>>>(a);
    k_msg_rec<<<MTILE, 256, 0, stream>>>(a);
    w_gruout<<<3125, 256, 0, stream>>>(a);
  }
}

// Round 8
// 700.802 us; speedup vs baseline: 3.8971x; 3.8971x over previous
//
#include <hip/hip_runtime.h>
#include <hip/hip_bf16.h>

#define N_NODES 50000
#define N_EDGES 800000
#define NC 16
#define FDIM 13
#define HID 32
#define RT_ROW 528       // 16 outputs * 32 hidden + 16 b2-terms (bf16)
#define EPB 64           // edges per msg tile
#define BSH 6            // bucket = 64 nodes
#define NBUCK 782        // ceil(50000/64)
#define CAP 1216         // slots per bucket (lambda=1024, +6 sigma, 19 tiles)
#define TPB 19           // tiles per bucket = CAP/EPB
#define NTILES (NBUCK * TPB)   // 14858
#define OVB 2            // overflow blocks appended to msg grid
#define OVCAP 2048

typedef unsigned short ushort_t;
typedef unsigned int uint_t;
typedef __attribute__((ext_vector_type(8))) unsigned short u16x8;

__device__ __forceinline__ float bf2f(ushort_t u) {
  union { unsigned int i; float f; } v; v.i = ((unsigned int)u) << 16; return v.f;
}
__device__ __forceinline__ ushort_t f2bf(float f) {
  union { unsigned int i; float f; } v; v.f = f;
  unsigned int r = v.i + 0x7FFFu + ((v.i >> 16) & 1u);   // RNE
  return (ushort_t)(r >> 16);
}
__device__ __forceinline__ float loadf(const void* p, int i, int isf32) {
  return isf32 ? ((const float*)p)[i] : bf2f(((const ushort_t*)p)[i]);
}
__device__ __forceinline__ float sigmoidf_(float x) { return 1.0f / (1.0f + __expf(-x)); }
__device__ __forceinline__ float tanhf_(float x) { return 1.0f - 2.0f / (__expf(2.0f * x) + 1.0f); }

struct MK {
  const void *hx_in, *ef; const int *src, *dst;
  const void *w1, *b1, *w2, *b2, *wih, *whh, *bihp, *bhhp;
  float *hx32, *agg, *deg; int *cnt, *ovfcnt, *ovf, *eidp;
  ushort_t *Rt; void *out;
};

// per-block dtype self-detection: decode low16 of first 256 u32 words of hx as
// bf16; fp32 data -> ~81% wild exponents, bf16-packed N(0,1) -> ~0.
__device__ __forceinline__ int detect_f32(const void* hx_in, int* dcnt) {
  int tid = threadIdx.x;
  if (tid == 0) *dcnt = 0;
  __syncthreads();
  uint_t lo = ((const uint_t*)hx_in)[tid] & 0xFFFFu;
  uint_t ex = (lo >> 7) & 0xFFu;
  int wild = (ex < 103u || ex > 151u) ? 1 : 0;
  if (lo == 0u || lo == 0x8000u) wild = 0;
  atomicAdd(dcnt, wild);
  __syncthreads();
  return (*dcnt > 64) ? 1 : 0;
}

// Rt row build for node = idx>>4, lane owns output o = idx&15.
// hxr[16] = node's hidden-state row; w2t staged [io][h] stride 36; b2s [256].
__device__ __forceinline__ void rt_row(const float* hxr, const float* w2t,
                                       const float* b2s, ushort_t* rowp, int o) {
  #pragma unroll
  for (int c = 0; c < 4; c++) {
    float a8[8] = {0, 0, 0, 0, 0, 0, 0, 0};
    #pragma unroll
    for (int i = 0; i < 16; i++) {
      const float* wp = &w2t[(i * 16 + o) * 36 + c * 8];
      float4 wa = *(const float4*)(wp);
      float4 wb = *(const float4*)(wp + 4);
      a8[0] += hxr[i] * wa.x; a8[1] += hxr[i] * wa.y; a8[2] += hxr[i] * wa.z; a8[3] += hxr[i] * wa.w;
      a8[4] += hxr[i] * wb.x; a8[5] += hxr[i] * wb.y; a8[6] += hxr[i] * wb.z; a8[7] += hxr[i] * wb.w;
    }
    u16x8 ov;
    #pragma unroll
    for (int j = 0; j < 8; j++) ov[j] = f2bf(a8[j]);
    *(u16x8*)(rowp + o * 32 + c * 8) = ov;
  }
  float vb = 0.0f;
  #pragma unroll
  for (int i = 0; i < 16; i++) vb += hxr[i] * b2s[i * 16 + o];
  rowp[512 + o] = f2bf(vb);
}

__device__ __forceinline__ void stage_w2(const MK& a, float* w2t, float* b2s, int isf32) {
  int tid = threadIdx.x;
  for (int k = tid; k < 256 * HID; k += 256) {
    int h = k >> 8, io = k & 255;
    w2t[io * 36 + h] = loadf(a.w2, h * 256 + io, isf32);
  }
  b2s[tid] = loadf(a.b2, tid, isf32);
}

// ==== kernel 1: detect + hx->fp32 + Rt build + agg zero + deg + bucket scatter ====
__global__ void __launch_bounds__(256) k_pre(MK a) {
  __shared__ float w2t[256 * 36];
  __shared__ float b2s[256];
  __shared__ float hx_l[16 * 17];
  __shared__ int dcnt;
  int tid = threadIdx.x;
  int isf32 = detect_f32(a.hx_in, &dcnt);
  stage_w2(a, w2t, b2s, isf32);

  int idx = blockIdx.x * 256 + tid;            // grid = 3125 -> covers 800000
  float hv = loadf(a.hx_in, idx, isf32);
  a.hx32[idx] = hv;
  int vl = tid >> 4, o = tid & 15;
  hx_l[vl * 17 + o] = hv;
  a.agg[idx] = 0.0f;

  // edge-side work (same index space: E == N*NC == 800000)
  int e = idx;
  int s = a.src[e], d = a.dst[e];
  atomicAdd(&a.deg[d], 1.0f);
  int b = s >> BSH;
  int p = atomicAdd(&a.cnt[b], 1);
  if (p < CAP) a.eidp[b * CAP + p] = e;
  else { int op = atomicAdd(a.ovfcnt, 1); if (op < OVCAP) a.ovf[op] = e; }
  __syncthreads();

  float hxr[16];
  #pragma unroll
  for (int i = 0; i < 16; i++) hxr[i] = hx_l[vl * 17 + i];
  rt_row(hxr, w2t, b2s, a.Rt + (size_t)(idx >> 4) * RT_ROW, o);
}

// ==== kernel 2/4: per-edge message over padded buckets + overflow tail ====
__global__ void __launch_bounds__(256) k_msg(MK a) {
  __shared__ float w1s[FDIM * HID];
  __shared__ float b1s[HID];
  __shared__ float efs[EPB * FDIM];
  __shared__ float hs[EPB * 33];
  __shared__ int seid[EPB], ssrc[EPB], sdst[EPB];
  __shared__ int dcnt;
  int tid = threadIdx.x;
  int isf32 = detect_f32(a.hx_in, &dcnt);
  for (int k = tid; k < FDIM * HID; k += 256) w1s[k] = loadf(a.w1, k, isf32);
  if (tid < HID) b1s[tid] = loadf(a.b1, tid, isf32);

  int t = blockIdx.x;
  if (t < NTILES) {
    int b = t / TPB, ls0 = (t % TPB) * EPB;
    int cb = a.cnt[b]; if (cb > CAP) cb = CAP;
    int nv = cb - ls0; if (nv <= 0) return;    // uniform: whole block exits
    if (nv > EPB) nv = EPB;
    if (tid < EPB) {
      int eid = (tid < nv) ? a.eidp[b * CAP + ls0 + tid] : 0;
      seid[tid] = eid; ssrc[tid] = a.src[eid]; sdst[tid] = a.dst[eid];
    }
    __syncthreads();
    #pragma unroll
    for (int q = 0; q < 4; q++) {
      int j = q * 256 + tid, le = j >> 4, i = j & 15;
      if (i < FDIM) efs[le * FDIM + i] = loadf(a.ef, seid[le] * FDIM + i, isf32);
    }
    __syncthreads();
    for (int v = tid; v < EPB * HID; v += 256) {
      int le = v >> 5, h = v & 31;
      float acc = b1s[h];
      #pragma unroll
      for (int i = 0; i < FDIM; i++) acc += efs[le * FDIM + i] * w1s[i * HID + h];
      hs[le * 33 + h] = fmaxf(acc, 0.0f);
    }
    __syncthreads();
    #pragma unroll
    for (int q = 0; q < 4; q++) {
      int item = q * 256 + tid, le = item >> 4, o = item & 15;
      if (le < nv) {
        int s = ssrc[le], d = sdst[le];
        const ushort_t* rrow = a.Rt + (size_t)s * RT_ROW;
        const u16x8* rr = (const u16x8*)(rrow + o * 32);
        float acc = bf2f(rrow[512 + o]);
        #pragma unroll
        for (int c = 0; c < 4; c++) {
          u16x8 rv = rr[c];
          #pragma unroll
          for (int j = 0; j < 8; j++) acc += hs[le * 33 + c * 8 + j] * bf2f(rv[j]);
        }
        atomicAdd(&a.agg[d * NC + o], acc);
      }
    }
  } else {
    // overflow edges (normally zero): full per-(edge,o) recompute
    int on = *a.ovfcnt; if (on > OVCAP) on = OVCAP;
    for (int i = (t - NTILES) * 256 + tid; i < on * NC; i += OVB * 256) {
      int e = a.ovf[i >> 4], o = i & 15;
      int s = a.src[e], d = a.dst[e];
      const ushort_t* rrow = a.Rt + (size_t)s * RT_ROW;
      float acc = bf2f(rrow[512 + o]);
      for (int h = 0; h < HID; h++) {
        float hv = b1s[h];
        for (int ii = 0; ii < FDIM; ii++) hv += loadf(a.ef, e * FDIM + ii, isf32) * w1s[ii * HID + h];
        acc += fmaxf(hv, 0.0f) * bf2f(rrow[o * 32 + h]);
      }
      atomicAdd(&a.agg[d * NC + o], acc);
    }
  }
}

// GRU weight staging transposed stride-17 (conflict-free) + core
__device__ __forceinline__ void stage_gru(const MK& a, float* wihT, float* whhT,
                                          float* bihs, float* bhhs, int isf32) {
  int tid = threadIdx.x;
  for (int kk = tid; kk < 3 * NC * NC; kk += 256) {
    int g = kk >> 8, rem = kk & 255, o = rem >> 4, k = rem & 15;
    wihT[g * 272 + k * 17 + o] = loadf(a.wih, kk, isf32);
    whhT[g * 272 + k * 17 + o] = loadf(a.whh, kk, isf32);
  }
  if (tid < 3 * NC) { bihs[tid] = loadf(a.bihp, tid, isf32); bhhs[tid] = loadf(a.bhhp, tid, isf32); }
}
__device__ __forceinline__ float gru_core(const float* wihT, const float* whhT,
                                          const float* bihs, const float* bhhs,
                                          const float* x, const float* h, int o) {
  float gir = bihs[o], giz = bihs[NC + o], gin = bihs[2 * NC + o];
  float ghr = bhhs[o], ghz = bhhs[NC + o], ghn = bhhs[2 * NC + o];
  #pragma unroll
  for (int k = 0; k < NC; k++) {
    gir += x[k] * wihT[k * 17 + o];
    giz += x[k] * wihT[272 + k * 17 + o];
    gin += x[k] * wihT[544 + k * 17 + o];
    ghr += h[k] * whhT[k * 17 + o];
    ghz += h[k] * whhT[272 + k * 17 + o];
    ghn += h[k] * whhT[544 + k * 17 + o];
  }
  float r = sigmoidf_(gir + ghr);
  float z = sigmoidf_(giz + ghz);
  float n = tanhf_(gin + r * ghn);
  return (1.0f - z) * n + z * h[o];
}
__device__ __forceinline__ void load_xh(const MK& a, int v, float inv, float* x, float* h) {
  const float4* ar = (const float4*)(a.agg + v * NC);
  const float4* hr = (const float4*)(a.hx32 + v * NC);
  #pragma unroll
  for (int q = 0; q < 4; q++) {
    float4 aa = ar[q], bb = hr[q];
    x[4 * q + 0] = aa.x * inv; x[4 * q + 1] = aa.y * inv; x[4 * q + 2] = aa.z * inv; x[4 * q + 3] = aa.w * inv;
    h[4 * q + 0] = bb.x; h[4 * q + 1] = bb.y; h[4 * q + 2] = bb.z; h[4 * q + 3] = bb.w;
  }
}

// ==== kernel 3: GRU update (in place) + Rt rebuild + agg re-zero ====
__global__ void __launch_bounds__(256) k_update(MK a) {
  __shared__ float w2t[256 * 36];
  __shared__ float b2s[256];
  __shared__ float wihT[816], whhT[816], bihs[48], bhhs[48];
  __shared__ float hx_l[16 * 17];
  __shared__ int dcnt;
  int tid = threadIdx.x;
  int isf32 = detect_f32(a.hx_in, &dcnt);
  stage_w2(a, w2t, b2s, isf32);
  stage_gru(a, wihT, whhT, bihs, bhhs, isf32);
  __syncthreads();

  int idx = blockIdx.x * 256 + tid;
  int v = idx >> 4, o = idx & 15, vl = tid >> 4;
  float inv = 1.0f / fmaxf(a.deg[v], 1.0f);
  float x[16], h[16];
  load_xh(a, v, inv, x, h);
  float hn = gru_core(wihT, whhT, bihs, bhhs, x, h, o);
  hx_l[vl * 17 + o] = hn;
  __syncthreads();                 // hx row fully read+staged before in-place write
  a.hx32[idx] = hn;
  a.agg[idx] = 0.0f;

  float hxr[16];
  #pragma unroll
  for (int i = 0; i < 16; i++) hxr[i] = hx_l[vl * 17 + i];
  rt_row(hxr, w2t, b2s, a.Rt + (size_t)v * RT_ROW, o);
}

// ==== kernel 5: final GRU -> d_out ====
__global__ void __launch_bounds__(256) k_gru(MK a) {
  __shared__ float wihT[816], whhT[816], bihs[48], bhhs[48];
  __shared__ int dcnt;
  int tid = threadIdx.x;
  int isf32 = detect_f32(a.hx_in, &dcnt);
  stage_gru(a, wihT, whhT, bihs, bhhs, isf32);
  __syncthreads();
  int idx = blockIdx.x * 256 + tid;
  int v = idx >> 4, o = idx & 15;
  float inv = 1.0f / fmaxf(a.deg[v], 1.0f);
  float x[16], h[16];
  load_xh(a, v, inv, x, h);
  float hn = gru_core(wihT, whhT, bihs, bhhs, x, h, o);
  if (isf32) ((float*)a.out)[idx] = hn;
  else       ((ushort_t*)a.out)[idx] = f2bf(hn);
}

extern "C" void kernel_launch(void* const* d_in, const int* in_sizes, int n_in,
                              void* d_out, int out_size, void* d_ws, size_t ws_size,
                              hipStream_t stream) {
  char* ws = (char*)d_ws;
  MK a;
  a.hx_in = d_in[0]; a.ef = d_in[1];
  a.src = (const int*)d_in[2]; a.dst = (const int*)d_in[3];
  a.w1 = d_in[4]; a.b1 = d_in[5]; a.w2 = d_in[6]; a.b2 = d_in[7];
  a.wih = d_in[8]; a.whh = d_in[9]; a.bihp = d_in[10]; a.bhhp = d_in[11];
  a.out = d_out;
  // layout (total 63,214,976 B):
  a.hx32   = (float*)(ws + 0);           //  3,200,000
  a.agg    = (float*)(ws + 3200000);     //  3,200,000
  a.deg    = (float*)(ws + 6400000);     //    200,000  -- zero region start
  a.cnt    = (int*)  (ws + 6600000);     //      3,128
  a.ovfcnt = (int*)  (ws + 6603128);     //          4
  a.ovf    = (int*)  (ws + 6603132);     //      8,192  -- zero region end
  a.eidp   = (int*)  (ws + 6611328);     //  3,803,648  (782*1216*4)
  a.Rt     = (ushort_t*)(ws + 10414976); // 52,800,000

  hipMemsetAsync(ws + 6400000, 0, 211328, stream);     // deg+cnt+ovfcnt(+ovf)
  k_pre<<<3125, 256, 0, stream>>>(a);
  k_msg<<<NTILES + OVB, 256, 0, stream>>>(a);
  k_update<<<3125, 256, 0, stream>>>(a);
  k_msg<<<NTILES + OVB, 256, 0, stream>>>(a);
  k_gru<<<3125, 256, 0, stream>>>(a);
}

// Round 9
// 491.998 us; speedup vs baseline: 5.5510x; 1.4244x over previous
//
#include <hip/hip_runtime.h>
#include <hip/hip_bf16.h>

#define N_NODES 50000
#define N_EDGES 800000
#define NC 16
#define FDIM 13
#define HID 32
#define RT_ROW 528     // 16 outputs * 32 hidden + 16 b2-terms (bf16)
#define EPB 64         // edges per msg tile
#define BSHIFT 3       // nodes per bucket = 8 (exact counting sort, R5/R6-proven)
#define NBUCK 6400     // ceil(50000/8) padded to 256*25
#define ZWORDS 56400   // deg(50000 f32) + hist(6400 i32)
#define MTILE 12500    // 800000/64 dense tiles

typedef unsigned short ushort_t;
typedef unsigned int uint_t;
typedef __attribute__((ext_vector_type(8))) unsigned short u16x8;

__device__ __forceinline__ float bf2f(ushort_t u) {
  union { unsigned int i; float f; } v; v.i = ((unsigned int)u) << 16; return v.f;
}
__device__ __forceinline__ ushort_t f2bf(float f) {
  union { unsigned int i; float f; } v; v.f = f;
  unsigned int r = v.i + 0x7FFFu + ((v.i >> 16) & 1u);   // RNE
  return (ushort_t)(r >> 16);
}
__device__ __forceinline__ float loadf(const void* p, int i, int isf32) {
  return isf32 ? ((const float*)p)[i] : bf2f(((const ushort_t*)p)[i]);
}
__device__ __forceinline__ float sigmoidf_(float x) { return 1.0f / (1.0f + __expf(-x)); }
__device__ __forceinline__ float tanhf_(float x) { return 1.0f - 2.0f / (__expf(2.0f * x) + 1.0f); }

// packed bf16 pair dot-accumulate: d = a.lo*b.lo + a.hi*b.hi + c
__device__ __forceinline__ float dot2bf(uint_t a, uint_t b, float c) {
  float d;
  asm("v_dot2_f32_bf16 %0, %1, %2, %3" : "=v"(d) : "v"(a), "v"(b), "v"(c));
  return d;
}

// ---- zero deg+hist; block 0 also runs the dtype detector (1 = fp32) ----
__global__ void k_init(const uint_t* __restrict__ hx_words, int* __restrict__ flag,
                       int* __restrict__ zbase) {
  int idx = blockIdx.x * 256 + threadIdx.x;
  if (idx < ZWORDS) zbase[idx] = 0;
  if (blockIdx.x == 0) {
    __shared__ int cnt;
    if (threadIdx.x == 0) cnt = 0;
    __syncthreads();
    uint_t lo = hx_words[threadIdx.x] & 0xFFFFu;
    uint_t ex = (lo >> 7) & 0xFFu;
    int wild = (ex < 103u || ex > 151u) ? 1 : 0;
    if (lo == 0u || lo == 0x8000u) wild = 0;
    atomicAdd(&cnt, wild);
    __syncthreads();
    if (threadIdx.x == 0) flag[0] = (cnt > 64) ? 1 : 0;
  }
}

// ---- hx->fp32 copy, dst-degree, src-bucket histogram ----
__global__ void k_pre(const void* __restrict__ hx_in, float* __restrict__ hx32,
                      const int* __restrict__ src, const int* __restrict__ dst,
                      float* __restrict__ deg, int* __restrict__ hist,
                      const int* __restrict__ flag) {
  int isf32 = flag[0];
  int idx = blockIdx.x * 256 + threadIdx.x;
  hx32[idx] = loadf(hx_in, idx, isf32);
  atomicAdd(&deg[dst[idx]], 1.0f);
  atomicAdd(&hist[src[idx] >> BSHIFT], 1);
}

// ---- fused: block 0 = exclusive scan of hist; blocks 1.. = Rt build + agg zero ----
__global__ void k_scan_rnode(int* __restrict__ hist, const float* __restrict__ hx,
                             const void* __restrict__ w2, const void* __restrict__ b2,
                             ushort_t* __restrict__ Rt, float* __restrict__ agg,
                             const int* __restrict__ flag, int sorted) {
  __shared__ int lds[NBUCK];
  __shared__ int psum[256];
  __shared__ float w2t[256 * 36];
  __shared__ float b2s[256];
  int tid = threadIdx.x;
  if (blockIdx.x == 0) {
    if (!sorted) return;
    for (int i = tid; i < NBUCK; i += 256) lds[i] = hist[i];
    __syncthreads();
    int base = tid * 25;
    int s = 0;
    #pragma unroll
    for (int i = 0; i < 25; i++) { int v = lds[base + i]; lds[base + i] = s; s += v; }
    psum[tid] = s;
    __syncthreads();
    if (tid == 0) { int run = 0; for (int i = 0; i < 256; i++) { int v = psum[i]; psum[i] = run; run += v; } }
    __syncthreads();
    int off = psum[tid];
    #pragma unroll
    for (int i = 0; i < 25; i++) lds[base + i] += off;
    __syncthreads();
    for (int i = tid; i < NBUCK; i += 256) hist[i] = lds[i];
    return;
  }
  int isf32 = flag[0];
  for (int k = tid; k < 256 * HID; k += 256) {
    int h = k >> 8, io = k & 255;
    w2t[io * 36 + h] = loadf(w2, h * 256 + io, isf32);
  }
  b2s[tid] = loadf(b2, tid, isf32);
  __syncthreads();
  int idx = (blockIdx.x - 1) * 256 + tid;        // covers N*NC exactly
  agg[idx] = 0.0f;
  int node = idx >> 4, o = idx & 15;

  float hxr[16];
  const float4* hp = (const float4*)(hx + node * NC);
  #pragma unroll
  for (int q = 0; q < 4; q++) {
    float4 t = hp[q];
    hxr[4 * q + 0] = t.x; hxr[4 * q + 1] = t.y; hxr[4 * q + 2] = t.z; hxr[4 * q + 3] = t.w;
  }
  ushort_t* rowp = Rt + (size_t)node * RT_ROW;
  #pragma unroll
  for (int c = 0; c < 4; c++) {
    float a[8] = {0, 0, 0, 0, 0, 0, 0, 0};
    #pragma unroll
    for (int i = 0; i < 16; i++) {
      const float* wp = &w2t[(i * 16 + o) * 36 + c * 8];
      float4 wa = *(const float4*)(wp);
      float4 wb = *(const float4*)(wp + 4);
      a[0] += hxr[i] * wa.x; a[1] += hxr[i] * wa.y; a[2] += hxr[i] * wa.z; a[3] += hxr[i] * wa.w;
      a[4] += hxr[i] * wb.x; a[5] += hxr[i] * wb.y; a[6] += hxr[i] * wb.z; a[7] += hxr[i] * wb.w;
    }
    u16x8 ov;
    #pragma unroll
    for (int j = 0; j < 8; j++) ov[j] = f2bf(a[j]);
    *(u16x8*)(rowp + o * 32 + c * 8) = ov;
  }
  float vb = 0.0f;
  #pragma unroll
  for (int i = 0; i < 16; i++) vb += hxr[i] * b2s[i * 16 + o];
  rowp[512 + o] = f2bf(vb);
}

// ---- scatter edges into bucket order (hist = running cursors), 8 B/edge ----
__global__ void k_scatter1(const int* __restrict__ src, const int* __restrict__ dst,
                           int* __restrict__ cursors, uint2* __restrict__ sortbuf) {
  int e = blockIdx.x * 256 + threadIdx.x;
  int s = src[e];
  int p = atomicAdd(&cursors[s >> BSHIFT], 1);
  uint2 rec; rec.x = ((uint_t)s << 16) | (uint_t)dst[e]; rec.y = (uint_t)e;
  sortbuf[p] = rec;
}

// ---- edge kernel: recompute MLP -> packed bf16 LDS, dot2 with Rt, scatter ----
__global__ void __launch_bounds__(256) k_msg(
    const int* __restrict__ src, const int* __restrict__ dst,
    const uint2* __restrict__ sortbuf, const void* __restrict__ ef,
    const void* __restrict__ w1, const void* __restrict__ b1,
    const ushort_t* __restrict__ Rt, float* __restrict__ agg,
    const int* __restrict__ flag, int sorted) {
  __shared__ float w1s[FDIM * HID];
  __shared__ float b1s[HID];
  __shared__ float efs[EPB * FDIM];
  __shared__ uint_t hsp[EPB * 20];     // 16 bf16-pairs per edge, stride 20 (16B-aligned rows)
  __shared__ int ssrc[EPB], sdst[EPB], seid[EPB];
  int isf32 = flag[0];
  int tid = threadIdx.x;
  int e0 = blockIdx.x * EPB;
  for (int k = tid; k < FDIM * HID; k += 256) w1s[k] = loadf(w1, k, isf32);
  if (tid < HID) b1s[tid] = loadf(b1, tid, isf32);
  if (tid < EPB) {
    if (sorted) {
      uint2 rec = sortbuf[e0 + tid];
      ssrc[tid] = (int)(rec.x >> 16); sdst[tid] = (int)(rec.x & 0xFFFFu);
      seid[tid] = (int)rec.y;
    } else {
      ssrc[tid] = src[e0 + tid]; sdst[tid] = dst[e0 + tid]; seid[tid] = e0 + tid;
    }
  }
  __syncthreads();
  #pragma unroll
  for (int q = 0; q < 4; q++) {
    int j = q * 256 + tid, le = j >> 4, i = j & 15;
    if (i < FDIM) efs[le * FDIM + i] = loadf(ef, seid[le] * FDIM + i, isf32);
  }
  __syncthreads();
  // hidden pairs: 64 edges * 16 pairs = 1024 items
  #pragma unroll
  for (int q = 0; q < 4; q++) {
    int v = q * 256 + tid;
    int le = v >> 4, hp2 = v & 15, h0 = hp2 * 2;
    float a0 = b1s[h0], a1 = b1s[h0 + 1];
    #pragma unroll
    for (int i = 0; i < FDIM; i++) {
      float e = efs[le * FDIM + i];
      a0 += e * w1s[i * HID + h0];
      a1 += e * w1s[i * HID + h0 + 1];
    }
    uint_t pk = (uint_t)f2bf(fmaxf(a0, 0.0f)) | ((uint_t)f2bf(fmaxf(a1, 0.0f)) << 16);
    hsp[le * 20 + hp2] = pk;
  }
  __syncthreads();
  #pragma unroll
  for (int q = 0; q < 4; q++) {
    int item = q * 256 + tid, le = item >> 4, o = item & 15;
    int s = ssrc[le], d = sdst[le];
    const ushort_t* rrow = Rt + (size_t)s * RT_ROW;
    const uint_t* ru = (const uint_t*)(rrow + o * 32);   // 16 bf16-pairs
    const uint_t* hp = &hsp[le * 20];
    float acc = bf2f(rrow[512 + o]);
    #pragma unroll
    for (int k = 0; k < 16; k++) acc = dot2bf(hp[k], ru[k], acc);
    atomicAdd(&agg[d * NC + o], acc);
  }
}

// GRU weight staging transposed stride-17 (conflict-free) + core
__device__ __forceinline__ void stage_gru(const void* w_ih, const void* w_hh,
                                          const void* b_ih, const void* b_hh,
                                          float* wihT, float* whhT,
                                          float* bih, float* bhh, int isf32, int tid) {
  for (int kk = tid; kk < 3 * NC * NC; kk += 256) {
    int g = kk >> 8, rem = kk & 255, o = rem >> 4, k = rem & 15;
    wihT[g * 272 + k * 17 + o] = loadf(w_ih, kk, isf32);
    whhT[g * 272 + k * 17 + o] = loadf(w_hh, kk, isf32);
  }
  if (tid < 3 * NC) { bih[tid] = loadf(b_ih, tid, isf32); bhh[tid] = loadf(b_hh, tid, isf32); }
}
__device__ __forceinline__ float gru_core(const float* wihT, const float* whhT,
                                          const float* bih, const float* bhh,
                                          const float* x, const float* h, int o) {
  float gir = bih[o], giz = bih[NC + o], gin = bih[2 * NC + o];
  float ghr = bhh[o], ghz = bhh[NC + o], ghn = bhh[2 * NC + o];
  #pragma unroll
  for (int k = 0; k < NC; k++) {
    gir += x[k] * wihT[k * 17 + o];
    giz += x[k] * wihT[272 + k * 17 + o];
    gin += x[k] * wihT[544 + k * 17 + o];
    ghr += h[k] * whhT[k * 17 + o];
    ghz += h[k] * whhT[272 + k * 17 + o];
    ghn += h[k] * whhT[544 + k * 17 + o];
  }
  float r = sigmoidf_(gir + ghr);
  float z = sigmoidf_(giz + ghz);
  float n = tanhf_(gin + r * ghn);
  return (1.0f - z) * n + z * h[o];
}

// ---- fused GRU + Rt rebuild + agg re-zero ----
__global__ void k_update(const float* __restrict__ agg_in, const float* __restrict__ deg,
                         float* __restrict__ hx, const void* __restrict__ w_ih,
                         const void* __restrict__ w_hh, const void* __restrict__ b_ih,
                         const void* __restrict__ b_hh, const void* __restrict__ w2,
                         const void* __restrict__ b2, ushort_t* __restrict__ Rt,
                         float* __restrict__ agg_out, const int* __restrict__ flag) {
  __shared__ float w2t[256 * 36];
  __shared__ float b2s[256];
  __shared__ float wihT[3 * 272], whhT[3 * 272], bih[3 * NC], bhh[3 * NC];
  __shared__ float hx_l[16 * 17];
  int isf32 = flag[0];
  int tid = threadIdx.x;
  for (int k = tid; k < 256 * HID; k += 256) {
    int h = k >> 8, io = k & 255;
    w2t[io * 36 + h] = loadf(w2, h * 256 + io, isf32);
  }
  b2s[tid] = loadf(b2, tid, isf32);
  stage_gru(w_ih, w_hh, b_ih, b_hh, wihT, whhT, bih, bhh, isf32, tid);
  __syncthreads();

  int idx = blockIdx.x * 256 + tid;
  int v = idx >> 4, o = idx & 15, vl = tid >> 4;
  float inv = 1.0f / fmaxf(deg[v], 1.0f);
  float x[16], h[16];
  const float4* ar = (const float4*)(agg_in + v * NC);
  const float4* hr = (const float4*)(hx + v * NC);
  #pragma unroll
  for (int q = 0; q < 4; q++) {
    float4 a = ar[q], b = hr[q];
    x[4 * q + 0] = a.x * inv; x[4 * q + 1] = a.y * inv; x[4 * q + 2] = a.z * inv; x[4 * q + 3] = a.w * inv;
    h[4 * q + 0] = b.x; h[4 * q + 1] = b.y; h[4 * q + 2] = b.z; h[4 * q + 3] = b.w;
  }
  float hn = gru_core(wihT, whhT, bih, bhh, x, h, o);
  hx_l[vl * 17 + o] = hn;
  __syncthreads();
  hx[idx] = hn;
  agg_out[idx] = 0.0f;

  float hxr[16];
  #pragma unroll
  for (int i = 0; i < 16; i++) hxr[i] = hx_l[vl * 17 + i];
  ushort_t* rowp = Rt + (size_t)v * RT_ROW;
  #pragma unroll
  for (int c = 0; c < 4; c++) {
    float a[8] = {0, 0, 0, 0, 0, 0, 0, 0};
    #pragma unroll
    for (int i = 0; i < 16; i++) {
      const float* wp = &w2t[(i * 16 + o) * 36 + c * 8];
      float4 wa = *(const float4*)(wp);
      float4 wb = *(const float4*)(wp + 4);
      a[0] += hxr[i] * wa.x; a[1] += hxr[i] * wa.y; a[2] += hxr[i] * wa.z; a[3] += hxr[i] * wa.w;
      a[4] += hxr[i] * wb.x; a[5] += hxr[i] * wb.y; a[6] += hxr[i] * wb.z; a[7] += hxr[i] * wb.w;
    }
    u16x8 ov;
    #pragma unroll
    for (int j = 0; j < 8; j++) ov[j] = f2bf(a[j]);
    *(u16x8*)(rowp + o * 32 + c * 8) = ov;
  }
  float vb = 0.0f;
  #pragma unroll
  for (int i = 0; i < 16; i++) vb += hxr[i] * b2s[i * 16 + o];
  rowp[512 + o] = f2bf(vb);
}

// ---- final GRU: writes d_out ----
__global__ void k_gru(const float* __restrict__ agg, const float* __restrict__ deg,
                      const float* __restrict__ hx, const void* __restrict__ w_ih,
                      const void* __restrict__ w_hh, const void* __restrict__ b_ih,
                      const void* __restrict__ b_hh, void* __restrict__ out,
                      const int* __restrict__ flag) {
  __shared__ float wihT[3 * 272], whhT[3 * 272], bih[3 * NC], bhh[3 * NC];
  int isf32 = flag[0];
  int tid = threadIdx.x;
  stage_gru(w_ih, w_hh, b_ih, b_hh, wihT, whhT, bih, bhh, isf32, tid);
  __syncthreads();
  int idx = blockIdx.x * 256 + tid;
  int v = idx >> 4, o = idx & 15;
  float inv = 1.0f / fmaxf(deg[v], 1.0f);
  float x[16], h[16];
  const float4* ar = (const float4*)(agg + v * NC);
  const float4* hr = (const float4*)(hx + v * NC);
  #pragma unroll
  for (int q = 0; q < 4; q++) {
    float4 a = ar[q], b = hr[q];
    x[4 * q + 0] = a.x * inv; x[4 * q + 1] = a.y * inv; x[4 * q + 2] = a.z * inv; x[4 * q + 3] = a.w * inv;
    h[4 * q + 0] = b.x; h[4 * q + 1] = b.y; h[4 * q + 2] = b.z; h[4 * q + 3] = b.w;
  }
  float hn = gru_core(wihT, whhT, bih, bhh, x, h, o);
  if (isf32) ((float*)out)[idx] = hn;
  else       ((ushort_t*)out)[idx] = f2bf(hn);
}

extern "C" void kernel_launch(void* const* d_in, const int* in_sizes, int n_in,
                              void* d_out, int out_size, void* d_ws, size_t ws_size,
                              hipStream_t stream) {
  const void* hx_in = d_in[0];
  const void* ef    = d_in[1];
  const int*  esrc  = (const int*)d_in[2];
  const int*  edst  = (const int*)d_in[3];
  const void* w1    = d_in[4];
  const void* b1    = d_in[5];
  const void* w2    = d_in[6];
  const void* b2    = d_in[7];
  const void* wih   = d_in[8];
  const void* whh   = d_in[9];
  const void* bih_g = d_in[10];
  const void* bhh_g = d_in[11];

  char* ws = (char*)d_ws;
  float* hx32 = (float*)(ws + 0);           //  3,200,000
  float* agg  = (float*)(ws + 3200000);     //  3,200,000
  int*   flag = (int*)  (ws + 6400000);     //        256
  float* deg  = (float*)(ws + 6400256);     //    200,000 (deg+hist = zero region)
  int*   hist = (int*)  (ws + 6600256);     //     25,600

  int sorted = (ws_size >= (size_t)65825856) ? 1 : 0;
  uint2* sortbuf; ushort_t* Rt;
  if (sorted) {
    sortbuf = (uint2*)(ws + 6625856);       //  6,400,000
    Rt      = (ushort_t*)(ws + 13025856);   // 52,800,000 -> ends 65,825,856 (R5/R6-proven fit)
  } else {
    sortbuf = (uint2*)(ws + 6625856);       // unused
    Rt      = (ushort_t*)(ws + 6625856);    // -> ends 59,425,856
  }

  k_init<<<(ZWORDS + 255) / 256, 256, 0, stream>>>((const uint_t*)hx_in, flag, (int*)deg);
  k_pre<<<N_EDGES / 256, 256, 0, stream>>>(hx_in, hx32, esrc, edst, deg, hist, flag);
  k_scan_rnode<<<(N_NODES * NC) / 256 + 1, 256, 0, stream>>>(hist, hx32, w2, b2, Rt, agg,
                                                             flag, sorted);
  if (sorted)
    k_scatter1<<<N_EDGES / 256, 256, 0, stream>>>(esrc, edst, hist, sortbuf);
  k_msg<<<MTILE, 256, 0, stream>>>(esrc, edst, sortbuf, ef, w1, b1, Rt, agg, flag, sorted);
  k_update<<<(N_NODES * NC) / 256, 256, 0, stream>>>(agg, deg, hx32, wih, whh, bih_g, bhh_g,
                                                     w2, b2, Rt, agg, flag);
  k_msg<<<MTILE, 256, 0, stream>>>(esrc, edst, sortbuf, ef, w1, b1, Rt, agg, flag, sorted);
  k_gru<<<(N_NODES * NC) / 256, 256, 0, stream>>>(agg, deg, hx32, wih, whh, bih_g, bhh_g,
                                                  d_out, flag);
}

// Round 10
// 418.788 us; speedup vs baseline: 6.5214x; 1.1748x over previous
//
#include <hip/hip_runtime.h>
#include <hip/hip_bf16.h>

#define N_NODES 50000
#define N_EDGES 800000
#define NC 16
#define FDIM 13
#define HID 32
#define RT_ROW 528     // 16 outputs * 32 hidden + 16 b2-terms (bf16)
#define EPB 64         // edges per msg tile

// big-ws path: padded-bucket sort (no scan, no separate scatter)
#define BSH 3          // bucket = 8 nodes, lambda = 128 edges
#define NBUCK 6250
#define CAP 192        // lambda + ~5.7 sigma; spill list covers the tail
#define TPB 3          // tiles per bucket = CAP/EPB
#define NTILES (NBUCK * TPB)   // 18750
#define OVB 2
#define OVCAP 4096

// fallback path (R9-proven): exact counting sort
#define NBUCK9 6400    // ceil(50000/8) padded to 256*25
#define MTILE 12500

typedef unsigned short ushort_t;
typedef unsigned int uint_t;
typedef __attribute__((ext_vector_type(8))) unsigned short u16x8;

__device__ __forceinline__ float bf2f(ushort_t u) {
  union { unsigned int i; float f; } v; v.i = ((unsigned int)u) << 16; return v.f;
}
__device__ __forceinline__ ushort_t f2bf(float f) {
  union { unsigned int i; float f; } v; v.f = f;
  unsigned int r = v.i + 0x7FFFu + ((v.i >> 16) & 1u);   // RNE
  return (ushort_t)(r >> 16);
}
__device__ __forceinline__ float loadf(const void* p, int i, int isf32) {
  return isf32 ? ((const float*)p)[i] : bf2f(((const ushort_t*)p)[i]);
}
__device__ __forceinline__ float sigmoidf_(float x) { return 1.0f / (1.0f + __expf(-x)); }
__device__ __forceinline__ float tanhf_(float x) { return 1.0f - 2.0f / (__expf(2.0f * x) + 1.0f); }

// packed bf16 pair dot-accumulate: d = a.lo*b.lo + a.hi*b.hi + c  (R9-proven)
__device__ __forceinline__ float dot2bf(uint_t a, uint_t b, float c) {
  float d;
  asm("v_dot2_f32_bf16 %0, %1, %2, %3" : "=v"(d) : "v"(a), "v"(b), "v"(c));
  return d;
}

// ballot-based dtype detect (1 = fp32 inputs); no LDS atomics (R8 lesson)
__device__ __forceinline__ int detect_f32(const void* hx_in) {
  __shared__ int wc[4];
  int tid = threadIdx.x;
  uint_t lo = ((const uint_t*)hx_in)[tid] & 0xFFFFu;
  uint_t ex = (lo >> 7) & 0xFFu;
  int wild = (ex < 103u || ex > 151u) && lo != 0u && lo != 0x8000u;
  unsigned long long m = __ballot(wild);
  if ((tid & 63) == 0) wc[tid >> 6] = __popcll(m);
  __syncthreads();
  int c = wc[0] + wc[1] + wc[2] + wc[3];
  __syncthreads();
  return c > 64;
}

__device__ __forceinline__ void stage_w2(const void* w2, const void* b2,
                                         float* w2t, float* b2s, int isf32) {
  int tid = threadIdx.x;
  for (int k = tid; k < 256 * HID; k += 256) {
    int h = k >> 8, io = k & 255;
    w2t[io * 36 + h] = loadf(w2, h * 256 + io, isf32);
  }
  b2s[tid] = loadf(b2, tid, isf32);
}

// Rt row build: lane owns output o; hxr[16] = node row; w2t [io][h] stride 36
__device__ __forceinline__ void rt_row(const float* hxr, const float* w2t,
                                       const float* b2s, ushort_t* rowp, int o) {
  #pragma unroll
  for (int c = 0; c < 4; c++) {
    float a8[8] = {0, 0, 0, 0, 0, 0, 0, 0};
    #pragma unroll
    for (int i = 0; i < 16; i++) {
      const float* wp = &w2t[(i * 16 + o) * 36 + c * 8];
      float4 wa = *(const float4*)(wp);
      float4 wb = *(const float4*)(wp + 4);
      a8[0] += hxr[i] * wa.x; a8[1] += hxr[i] * wa.y; a8[2] += hxr[i] * wa.z; a8[3] += hxr[i] * wa.w;
      a8[4] += hxr[i] * wb.x; a8[5] += hxr[i] * wb.y; a8[6] += hxr[i] * wb.z; a8[7] += hxr[i] * wb.w;
    }
    u16x8 ov;
    #pragma unroll
    for (int j = 0; j < 8; j++) ov[j] = f2bf(a8[j]);
    *(u16x8*)(rowp + o * 32 + c * 8) = ov;
  }
  float vb = 0.0f;
  #pragma unroll
  for (int i = 0; i < 16; i++) vb += hxr[i] * b2s[i * 16 + o];
  rowp[512 + o] = f2bf(vb);
}

// ============ BIG PATH ============
// kernel 1: detect + hx->fp32 + agg zero + deg + MLP hidden (edge order,
// coalesced) + padded-bucket scatter + Rt build (LDS hx handoff)
__global__ void __launch_bounds__(256) k_pre_big(
    const void* __restrict__ hx_in, const void* __restrict__ ef,
    const int* __restrict__ src, const int* __restrict__ dst,
    const void* __restrict__ w1, const void* __restrict__ b1,
    const void* __restrict__ w2, const void* __restrict__ b2,
    float* __restrict__ hx32, float* __restrict__ agg, float* __restrict__ deg,
    int* __restrict__ cnt, int* __restrict__ ovfcnt, int* __restrict__ ovf,
    uint2* __restrict__ sortbuf, ushort_t* __restrict__ hidden,
    ushort_t* __restrict__ Rt) {
  __shared__ float w1s[FDIM * HID];
  __shared__ float b1s[HID];
  __shared__ float w2t[256 * 36];
  __shared__ float b2s[256];
  __shared__ float hx_l[16 * 17];
  int tid = threadIdx.x;
  int isf32 = detect_f32(hx_in);
  for (int k = tid; k < FDIM * HID; k += 256) w1s[k] = loadf(w1, k, isf32);
  if (tid < HID) b1s[tid] = loadf(b1, tid, isf32);
  stage_w2(w2, b2, w2t, b2s, isf32);

  int idx = blockIdx.x * 256 + tid;            // grid 3125 covers E == N*NC
  int vl = tid >> 4, o = tid & 15;
  float hv = loadf(hx_in, idx, isf32);
  hx32[idx] = hv;
  hx_l[vl * 17 + o] = hv;
  agg[idx] = 0.0f;

  int e = idx;
  int s = src[e], d = dst[e];
  atomicAdd(&deg[d], 1.0f);
  int b = s >> BSH;
  int p = atomicAdd(&cnt[b], 1);               // 6250 counters: R5-proven contention
  if (p < CAP) {
    uint2 rec; rec.x = ((uint_t)s << 16) | (uint_t)d; rec.y = (uint_t)e;
    sortbuf[b * CAP + p] = rec;
  } else {
    int op = atomicAdd(ovfcnt, 1);
    if (op < OVCAP) ovf[op] = e;
  }

  float efr[FDIM];
  #pragma unroll
  for (int i = 0; i < FDIM; i++) efr[i] = loadf(ef, e * FDIM + i, isf32);
  __syncthreads();                             // w1s/b1s/w2t staged; hx_l filled
  u16x8* hrow = (u16x8*)(hidden + (size_t)e * HID);
  #pragma unroll
  for (int c = 0; c < 4; c++) {
    u16x8 ov;
    #pragma unroll
    for (int j = 0; j < 8; j++) {
      int h = c * 8 + j;
      float acc = b1s[h];
      #pragma unroll
      for (int i = 0; i < FDIM; i++) acc += efr[i] * w1s[i * HID + h];
      ov[j] = f2bf(fmaxf(acc, 0.0f));
    }
    hrow[c] = ov;
  }

  float hxr[16];
  #pragma unroll
  for (int i = 0; i < 16; i++) hxr[i] = hx_l[vl * 17 + i];
  rt_row(hxr, w2t, b2s, Rt + (size_t)(idx >> 4) * RT_ROW, o);
}

// kernel 2/4: per-edge message — gather 64 B hidden rows, dot2 with Rt, scatter
__global__ void __launch_bounds__(256) k_msg_big(
    const int* __restrict__ src, const int* __restrict__ dst,
    const int* __restrict__ cnt, const int* __restrict__ ovfcnt,
    const int* __restrict__ ovf, const uint2* __restrict__ sortbuf,
    const ushort_t* __restrict__ hidden, const ushort_t* __restrict__ Rt,
    float* __restrict__ agg) {
  __shared__ uint_t hsp[EPB * 20];             // 16 bf16-pairs/edge, stride 20
  __shared__ int ssrc[EPB], sdst[EPB], seid[EPB];
  int tid = threadIdx.x;
  int t = blockIdx.x;
  if (t < NTILES) {
    int b = t / TPB, ls0 = (t - b * TPB) * EPB;
    int cb = cnt[b]; if (cb > CAP) cb = CAP;
    int nv = cb - ls0; if (nv <= 0) return;    // uniform early exit
    if (nv > EPB) nv = EPB;
    if (tid < EPB) {
      uint2 rec;
      if (tid < nv) rec = sortbuf[b * CAP + ls0 + tid];
      else { rec.x = 0u; rec.y = 0u; }
      ssrc[tid] = (int)(rec.x >> 16); sdst[tid] = (int)(rec.x & 0xFFFFu);
      seid[tid] = (int)rec.y;
    }
    __syncthreads();
    {
      int row = tid >> 2, chunk = tid & 3;     // 4 lanes per 64 B row
      uint4 hv = ((const uint4*)(hidden + (size_t)seid[row] * HID))[chunk];
      int base = row * 20 + chunk * 4;
      hsp[base] = hv.x; hsp[base + 1] = hv.y; hsp[base + 2] = hv.z; hsp[base + 3] = hv.w;
    }
    __syncthreads();
    #pragma unroll
    for (int q = 0; q < 4; q++) {
      int item = q * 256 + tid, le = item >> 4, o = item & 15;
      if (le < nv) {
        int s = ssrc[le], d = sdst[le];
        const ushort_t* rrow = Rt + (size_t)s * RT_ROW;
        const uint_t* ru = (const uint_t*)(rrow + o * 32);
        const uint_t* hp = &hsp[le * 20];
        float acc = bf2f(rrow[512 + o]);
        #pragma unroll
        for (int k = 0; k < 16; k++) acc = dot2bf(hp[k], ru[k], acc);
        atomicAdd(&agg[d * NC + o], acc);
      }
    }
  } else {
    // spill edges (normally zero)
    int on = *ovfcnt; if (on > OVCAP) on = OVCAP;
    for (int i = (t - NTILES) * 256 + tid; i < on * NC; i += OVB * 256) {
      int e = ovf[i >> 4], o = i & 15;
      int s = src[e], d = dst[e];
      const ushort_t* rrow = Rt + (size_t)s * RT_ROW;
      const uint_t* ru = (const uint_t*)(rrow + o * 32);
      const uint_t* hp = (const uint_t*)(hidden + (size_t)e * HID);
      float acc = bf2f(rrow[512 + o]);
      for (int k = 0; k < 16; k++) acc = dot2bf(hp[k], ru[k], acc);
      atomicAdd(&agg[d * NC + o], acc);
    }
  }
}

// ============ GRU (shared by both paths) ============
__device__ __forceinline__ void stage_gru(const void* w_ih, const void* w_hh,
                                          const void* b_ih, const void* b_hh,
                                          float* wihT, float* whhT,
                                          float* bih, float* bhh, int isf32, int tid) {
  for (int kk = tid; kk < 3 * NC * NC; kk += 256) {
    int g = kk >> 8, rem = kk & 255, o = rem >> 4, k = rem & 15;
    wihT[g * 272 + k * 17 + o] = loadf(w_ih, kk, isf32);
    whhT[g * 272 + k * 17 + o] = loadf(w_hh, kk, isf32);
  }
  if (tid < 3 * NC) { bih[tid] = loadf(b_ih, tid, isf32); bhh[tid] = loadf(b_hh, tid, isf32); }
}
__device__ __forceinline__ float gru_core(const float* wihT, const float* whhT,
                                          const float* bih, const float* bhh,
                                          const float* x, const float* h, int o) {
  float gir = bih[o], giz = bih[NC + o], gin = bih[2 * NC + o];
  float ghr = bhh[o], ghz = bhh[NC + o], ghn = bhh[2 * NC + o];
  #pragma unroll
  for (int k = 0; k < NC; k++) {
    gir += x[k] * wihT[k * 17 + o];
    giz += x[k] * wihT[272 + k * 17 + o];
    gin += x[k] * wihT[544 + k * 17 + o];
    ghr += h[k] * whhT[k * 17 + o];
    ghz += h[k] * whhT[272 + k * 17 + o];
    ghn += h[k] * whhT[544 + k * 17 + o];
  }
  float r = sigmoidf_(gir + ghr);
  float z = sigmoidf_(giz + ghz);
  float n = tanhf_(gin + r * ghn);
  return (1.0f - z) * n + z * h[o];
}
__device__ __forceinline__ void load_xh(const float* agg, const float* hx, int v,
                                        float inv, float* x, float* h) {
  const float4* ar = (const float4*)(agg + v * NC);
  const float4* hr = (const float4*)(hx + v * NC);
  #pragma unroll
  for (int q = 0; q < 4; q++) {
    float4 aa = ar[q], bb = hr[q];
    x[4 * q + 0] = aa.x * inv; x[4 * q + 1] = aa.y * inv; x[4 * q + 2] = aa.z * inv; x[4 * q + 3] = aa.w * inv;
    h[4 * q + 0] = bb.x; h[4 * q + 1] = bb.y; h[4 * q + 2] = bb.z; h[4 * q + 3] = bb.w;
  }
}

// kernel 3: GRU update (in place) + Rt rebuild + agg re-zero
__global__ void __launch_bounds__(256) k_update(
    const void* __restrict__ hx_in, const float* __restrict__ agg_in,
    const float* __restrict__ deg, float* __restrict__ hx,
    const void* __restrict__ w_ih, const void* __restrict__ w_hh,
    const void* __restrict__ b_ih, const void* __restrict__ b_hh,
    const void* __restrict__ w2, const void* __restrict__ b2,
    ushort_t* __restrict__ Rt, float* __restrict__ agg_out) {
  __shared__ float w2t[256 * 36];
  __shared__ float b2s[256];
  __shared__ float wihT[816], whhT[816], bih[48], bhh[48];
  __shared__ float hx_l[16 * 17];
  int tid = threadIdx.x;
  int isf32 = detect_f32(hx_in);
  stage_w2(w2, b2, w2t, b2s, isf32);
  stage_gru(w_ih, w_hh, b_ih, b_hh, wihT, whhT, bih, bhh, isf32, tid);
  __syncthreads();

  int idx = blockIdx.x * 256 + tid;
  int v = idx >> 4, o = idx & 15, vl = tid >> 4;
  float inv = 1.0f / fmaxf(deg[v], 1.0f);
  float x[16], h[16];
  load_xh(agg_in, hx, v, inv, x, h);
  float hn = gru_core(wihT, whhT, bih, bhh, x, h, o);
  hx_l[vl * 17 + o] = hn;
  __syncthreads();                 // hx row fully read+staged before in-place write
  hx[idx] = hn;
  agg_out[idx] = 0.0f;

  float hxr[16];
  #pragma unroll
  for (int i = 0; i < 16; i++) hxr[i] = hx_l[vl * 17 + i];
  rt_row(hxr, w2t, b2s, Rt + (size_t)v * RT_ROW, o);
}

// kernel 5: final GRU -> d_out
__global__ void __launch_bounds__(256) k_gru(
    const void* __restrict__ hx_in, const float* __restrict__ agg,
    const float* __restrict__ deg, const float* __restrict__ hx,
    const void* __restrict__ w_ih, const void* __restrict__ w_hh,
    const void* __restrict__ b_ih, const void* __restrict__ b_hh,
    void* __restrict__ out) {
  __shared__ float wihT[816], whhT[816], bih[48], bhh[48];
  int tid = threadIdx.x;
  int isf32 = detect_f32(hx_in);
  stage_gru(w_ih, w_hh, b_ih, b_hh, wihT, whhT, bih, bhh, isf32, tid);
  __syncthreads();
  int idx = blockIdx.x * 256 + tid;
  int v = idx >> 4, o = idx & 15;
  float inv = 1.0f / fmaxf(deg[v], 1.0f);
  float x[16], h[16];
  load_xh(agg, hx, v, inv, x, h);
  float hn = gru_core(wihT, whhT, bih, bhh, x, h, o);
  if (isf32) ((float*)out)[idx] = hn;
  else       ((ushort_t*)out)[idx] = f2bf(hn);
}

// ============ FALLBACK PATH (R9-proven, detect inline) ============
__global__ void k_pre9(const void* __restrict__ hx_in, float* __restrict__ hx32,
                       const int* __restrict__ src, const int* __restrict__ dst,
                       float* __restrict__ deg, int* __restrict__ hist) {
  int isf32 = detect_f32(hx_in);
  int idx = blockIdx.x * 256 + threadIdx.x;
  hx32[idx] = loadf(hx_in, idx, isf32);
  atomicAdd(&deg[dst[idx]], 1.0f);
  atomicAdd(&hist[src[idx] >> BSH], 1);
}

__global__ void k_scan_rnode9(const void* __restrict__ hx_in, int* __restrict__ hist,
                              const float* __restrict__ hx, const void* __restrict__ w2,
                              const void* __restrict__ b2, ushort_t* __restrict__ Rt,
                              float* __restrict__ agg) {
  __shared__ int lds[NBUCK9];
  __shared__ int psum[256];
  __shared__ float w2t[256 * 36];
  __shared__ float b2s[256];
  int tid = threadIdx.x;
  if (blockIdx.x == 0) {
    for (int i = tid; i < NBUCK9; i += 256) lds[i] = hist[i];
    __syncthreads();
    int base = tid * 25, s = 0;
    #pragma unroll
    for (int i = 0; i < 25; i++) { int v = lds[base + i]; lds[base + i] = s; s += v; }
    psum[tid] = s;
    __syncthreads();
    if (tid == 0) { int run = 0; for (int i = 0; i < 256; i++) { int v = psum[i]; psum[i] = run; run += v; } }
    __syncthreads();
    int off = psum[tid];
    #pragma unroll
    for (int i = 0; i < 25; i++) lds[base + i] += off;
    __syncthreads();
    for (int i = tid; i < NBUCK9; i += 256) hist[i] = lds[i];
    return;
  }
  int isf32 = detect_f32(hx_in);
  stage_w2(w2, b2, w2t, b2s, isf32);
  __syncthreads();
  int idx = (blockIdx.x - 1) * 256 + tid;
  agg[idx] = 0.0f;
  int node = idx >> 4, o = idx & 15;
  float hxr[16];
  const float4* hp = (const float4*)(hx + node * NC);
  #pragma unroll
  for (int q = 0; q < 4; q++) {
    float4 t = hp[q];
    hxr[4 * q + 0] = t.x; hxr[4 * q + 1] = t.y; hxr[4 * q + 2] = t.z; hxr[4 * q + 3] = t.w;
  }
  rt_row(hxr, w2t, b2s, Rt + (size_t)node * RT_ROW, o);
}

__global__ void k_scatter9(const int* __restrict__ src, const int* __restrict__ dst,
                           int* __restrict__ cursors, uint2* __restrict__ sortbuf) {
  int e = blockIdx.x * 256 + threadIdx.x;
  int s = src[e];
  int p = atomicAdd(&cursors[s >> BSH], 1);
  uint2 rec; rec.x = ((uint_t)s << 16) | (uint_t)dst[e]; rec.y = (uint_t)e;
  sortbuf[p] = rec;
}

__global__ void __launch_bounds__(256) k_msg9(
    const void* __restrict__ hx_in, const uint2* __restrict__ sortbuf,
    const void* __restrict__ ef, const void* __restrict__ w1,
    const void* __restrict__ b1, const ushort_t* __restrict__ Rt,
    float* __restrict__ agg) {
  __shared__ float w1s[FDIM * HID];
  __shared__ float b1s[HID];
  __shared__ float efs[EPB * FDIM];
  __shared__ uint_t hsp[EPB * 20];
  __shared__ int ssrc[EPB], sdst[EPB], seid[EPB];
  int tid = threadIdx.x;
  int isf32 = detect_f32(hx_in);
  int e0 = blockIdx.x * EPB;
  for (int k = tid; k < FDIM * HID; k += 256) w1s[k] = loadf(w1, k, isf32);
  if (tid < HID) b1s[tid] = loadf(b1, tid, isf32);
  if (tid < EPB) {
    uint2 rec = sortbuf[e0 + tid];
    ssrc[tid] = (int)(rec.x >> 16); sdst[tid] = (int)(rec.x & 0xFFFFu);
    seid[tid] = (int)rec.y;
  }
  __syncthreads();
  #pragma unroll
  for (int q = 0; q < 4; q++) {
    int j = q * 256 + tid, le = j >> 4, i = j & 15;
    if (i < FDIM) efs[le * FDIM + i] = loadf(ef, seid[le] * FDIM + i, isf32);
  }
  __syncthreads();
  #pragma unroll
  for (int q = 0; q < 4; q++) {
    int v = q * 256 + tid;
    int le = v >> 4, hp2 = v & 15, h0 = hp2 * 2;
    float a0 = b1s[h0], a1 = b1s[h0 + 1];
    #pragma unroll
    for (int i = 0; i < FDIM; i++) {
      float e = efs[le * FDIM + i];
      a0 += e * w1s[i * HID + h0];
      a1 += e * w1s[i * HID + h0 + 1];
    }
    hsp[le * 20 + hp2] = (uint_t)f2bf(fmaxf(a0, 0.0f)) | ((uint_t)f2bf(fmaxf(a1, 0.0f)) << 16);
  }
  __syncthreads();
  #pragma unroll
  for (int q = 0; q < 4; q++) {
    int item = q * 256 + tid, le = item >> 4, o = item & 15;
    int s = ssrc[le], d = sdst[le];
    const ushort_t* rrow = Rt + (size_t)s * RT_ROW;
    const uint_t* ru = (const uint_t*)(rrow + o * 32);
    const uint_t* hp = &hsp[le * 20];
    float acc = bf2f(rrow[512 + o]);
    #pragma unroll
    for (int k = 0; k < 16; k++) acc = dot2bf(hp[k], ru[k], acc);
    atomicAdd(&agg[d * NC + o], acc);
  }
}

extern "C" void kernel_launch(void* const* d_in, const int* in_sizes, int n_in,
                              void* d_out, int out_size, void* d_ws, size_t ws_size,
                              hipStream_t stream) {
  const void* hx_in = d_in[0];
  const void* ef    = d_in[1];
  const int*  esrc  = (const int*)d_in[2];
  const int*  edst  = (const int*)d_in[3];
  const void* w1    = d_in[4];
  const void* b1    = d_in[5];
  const void* w2    = d_in[6];
  const void* b2    = d_in[7];
  const void* wih   = d_in[8];
  const void* whh   = d_in[9];
  const void* bih_g = d_in[10];
  const void* bhh_g = d_in[11];

  char* ws = (char*)d_ws;
  float* hx32   = (float*)(ws + 0);          //  3,200,000
  float* agg    = (float*)(ws + 3200000);    //  3,200,000
  float* deg    = (float*)(ws + 6400000);    //    200,000  -- zero region start
  int*   cnt    = (int*)  (ws + 6600000);    //     25,600  (cnt / hist)
  int*   ovfcnt = (int*)  (ws + 6625600);    //         32  -- zero region end
  int*   ovf    = (int*)  (ws + 6625632);    //     16,384
  // big path layout:
  uint2*    sortbufB = (uint2*)(ws + 6642016);       //  9,600,000 (6250*192*8)
  ushort_t* hiddenB  = (ushort_t*)(ws + 16242016);   // 51,200,000
  ushort_t* RtB      = (ushort_t*)(ws + 67442016);   // 52,800,000 -> 120,242,016
  // fallback layout:
  uint2*    sortbuf9 = (uint2*)(ws + 6642016);       //  6,400,000
  ushort_t* Rt9      = (ushort_t*)(ws + 13042016);   // 52,800,000 -> 65,842,016

  int big = (ws_size >= (size_t)120242016);
  hipMemsetAsync(ws + 6400000, 0, 225632, stream);   // deg + cnt + ovfcnt

  if (big) {
    k_pre_big<<<3125, 256, 0, stream>>>(hx_in, ef, esrc, edst, w1, b1, w2, b2,
                                        hx32, agg, deg, cnt, ovfcnt, ovf,
                                        sortbufB, hiddenB, RtB);
    k_msg_big<<<NTILES + OVB, 256, 0, stream>>>(esrc, edst, cnt, ovfcnt, ovf,
                                                sortbufB, hiddenB, RtB, agg);
    k_update<<<3125, 256, 0, stream>>>(hx_in, agg, deg, hx32, wih, whh, bih_g, bhh_g,
                                       w2, b2, RtB, agg);
    k_msg_big<<<NTILES + OVB, 256, 0, stream>>>(esrc, edst, cnt, ovfcnt, ovf,
                                                sortbufB, hiddenB, RtB, agg);
    k_gru<<<3125, 256, 0, stream>>>(hx_in, agg, deg, hx32, wih, whh, bih_g, bhh_g, d_out);
  } else {
    k_pre9<<<3125, 256, 0, stream>>>(hx_in, hx32, esrc, edst, deg, cnt);
    k_scan_rnode9<<<3126, 256, 0, stream>>>(hx_in, cnt, hx32, w2, b2, Rt9, agg);
    k_scatter9<<<3125, 256, 0, stream>>>(esrc, edst, cnt, sortbuf9);
    k_msg9<<<MTILE, 256, 0, stream>>>(hx_in, sortbuf9, ef, w1, b1, Rt9, agg);
    k_update<<<3125, 256, 0, stream>>>(hx_in, agg, deg, hx32, wih, whh, bih_g, bhh_g,
                                       w2, b2, Rt9, agg);
    k_msg9<<<MTILE, 256, 0, stream>>>(hx_in, sortbuf9, ef, w1, b1, Rt9, agg);
    k_gru<<<3125, 256, 0, stream>>>(hx_in, agg, deg, hx32, wih, whh, bih_g, bhh_g, d_out);
  }
}